// Round 9
// baseline (637.221 us; speedup 1.0000x reference)
//
#include <hip/hip_runtime.h>
#include <hip/hip_bf16.h>
#include <cstdint>

// Problem constants (fixed by the reference)
#define NB 4
#define NH 128
#define NW 128
#define NC 256
#define NFF 1024
#define NE 4
#define NPATCH 4096   // B * 32 * 32
#define NPAIR 16      // ordered expert pairs (i1*4+i2), 12 valid
#define PPB 4         // patches per ffn block
#define BM 64         // token rows per ffn block (PPB*16)
#define FFC 128       // FF chunk streamed through LDS
#define NCHUNK_TOT 16 // 2 experts x (NFF/FFC)

typedef __attribute__((ext_vector_type(8))) short short8;
typedef __attribute__((ext_vector_type(8))) unsigned short ushort8;
typedef __attribute__((ext_vector_type(4))) float f32x4;

__device__ __forceinline__ unsigned short f2b(float f) {
  union { float f; uint32_t u; } v; v.f = f;
  uint32_t u = v.u + 0x7FFFu + ((v.u >> 16) & 1u);   // RNE
  return (unsigned short)(u >> 16);
}

// tanh-form GELU via sigmoid: x * sigmoid(1.5957691(x + 0.044715 x^3))
__device__ __forceinline__ float gelu_f(float v) {
  float u = v * v;
  float t = __builtin_fmaf(u, 0.044715f, 1.0f) * v;
  float e = __builtin_amdgcn_exp2f(t * -2.3022083f);   // exp(-1.59577*t)
  return v * __builtin_amdgcn_rcpf(1.0f + e);
}

// barrier that drains LDS ops only (no vmcnt drain -> global loads stay in flight)
__device__ __forceinline__ void bar_lgkm() {
  asm volatile("s_waitcnt lgkmcnt(0)" ::: "memory");
  __builtin_amdgcn_s_barrier();
}

// ---------------- weight fp32 -> bf16 (+ cnt zeroing) ----------------
__global__ __launch_bounds__(256) void convert_kernel(
    const float* __restrict__ W1, const float* __restrict__ W2,
    unsigned short* __restrict__ W1b, unsigned short* __restrict__ W2b,
    int* __restrict__ cnt, int n) {
  int i = blockIdx.x * blockDim.x + threadIdx.x;
  if (i < NPAIR) cnt[i] = 0;
  if (i < n) {
    W1b[i] = f2b(W1[i]);
    W2b[i] = f2b(W2[i]);
  }
}

// ---------------- router: means -> logits -> softmax -> top2 -> pair bins ----------------
__global__ __launch_bounds__(256) void router_kernel(
    const float* __restrict__ x, const float* __restrict__ Wg,
    int* __restrict__ cnt, int* __restrict__ plist, float2* __restrict__ wlist) {
  int p = blockIdx.x;                 // 0..4095
  int b = p >> 10, pi = p & 1023;
  int phi = pi >> 5, pwi = pi & 31;
  int c = threadIdx.x;                // 0..255 = channel

  const float* base = x + (((size_t)(b * NH + phi * 4) * NW) + pwi * 4) * NC + c;
  float s = 0.f;
#pragma unroll
  for (int i = 0; i < 4; i++)
#pragma unroll
    for (int j = 0; j < 4; j++)
      s += base[(i * NW + j) * NC];
  float mean = s * (1.f / 16.f);

  __shared__ float m_lds[NC];
  __shared__ double logit_lds[NE];
  m_lds[c] = mean;
  __syncthreads();

  int wid = c >> 6, lane = c & 63;    // wave w computes logit for expert w
  {
    const float* wg = Wg + wid * NC;
    double acc = 0.0;
#pragma unroll
    for (int q = 0; q < 4; q++)
      acc += (double)m_lds[lane + q * 64] * (double)wg[lane + q * 64];
    for (int off = 32; off; off >>= 1) acc += __shfl_down(acc, off);
    if (lane == 0) logit_lds[wid] = acc;
  }
  __syncthreads();

  if (c == 0) {
    double l[NE], pp[NE];
    double mx = -1e300;
#pragma unroll
    for (int i = 0; i < NE; i++) { l[i] = logit_lds[i]; mx = fmax(mx, l[i]); }
    double sum = 0.0;
#pragma unroll
    for (int i = 0; i < NE; i++) { pp[i] = exp(l[i] - mx); sum += pp[i]; }
#pragma unroll
    for (int i = 0; i < NE; i++) pp[i] /= sum;
    // top-2, ties -> lower index (lax.top_k semantics)
    int i1 = 0; double p1 = pp[0];
    for (int i = 1; i < NE; i++) if (pp[i] > p1) { p1 = pp[i]; i1 = i; }
    int i2 = -1; double p2 = -1.0;
    for (int i = 0; i < NE; i++) {
      if (i == i1) continue;
      if (pp[i] > p2) { p2 = pp[i]; i2 = i; }
    }
    double den = p1 + p2 + 1e-9;
    float w1 = (float)(p1 / den), w2 = (float)(p2 / den);
    int pr = i1 * NE + i2;                         // ordered pair bin
    int pos = atomicAdd(&cnt[pr], 1);
    plist[pr * NPATCH + pos] = p;
    wlist[pr * NPATCH + pos] = make_float2(w1, w2);
  }
}

// ---------------- worklist: XCD-affine padded slots ----------------
// class x (0..7) covers bins {x, x+8}; slot s -> class s%8 (blockIdx%8 ~ XCD).
// wl[0] = slot count (8 * max class tiles); wl[1+s] = (pr<<12)|pbase or -1.
__global__ __launch_bounds__(64) void worklist_kernel(
    const int* __restrict__ cnt, int* __restrict__ wl) {
  int lane = threadIdx.x;
  int cA[8], cB[8], mx = 0;
#pragma unroll
  for (int xc = 0; xc < 8; ++xc) {
    cA[xc] = (cnt[xc] + PPB - 1) / PPB;
    cB[xc] = (cnt[xc + 8] + PPB - 1) / PPB;
    int t = cA[xc] + cB[xc];
    mx = (t > mx) ? t : mx;
  }
  if (lane == 0) wl[0] = 8 * mx;
  int x = lane & 7, sub = lane >> 3;     // 8 writer lanes per class
  int nA = cA[x], tot = cA[x] + cB[x];
  for (int r = sub; r < mx; r += 8) {
    int ent = -1;
    if (r < nA) ent = (x << 12) | (r * PPB);
    else if (r < tot) ent = ((x + 8) << 12) | ((r - nA) * PPB);
    wl[1 + x + 8 * r] = ent;
  }
}

// ---------------- pair-FFN, producer/consumer wave specialization ----------------
// 512 thr / 8 waves, 64 KiB LDS -> 2 blocks/CU. Waves 0-3 (G1): GEMM1 (swapped,
// H^T = W1*X^T, f-strip 32) + bias + GELU + router-weight scale -> dbuf Hl.
// NEW (R9): each G1 wave preloads the ks=0..3 X fragments into registers once
// per block (64 VGPR, reused across all 16 chunks) -> GEMM1 inner loop for
// ks 0-3 has ZERO LDS reads (pure global-load + MFMA), halving GEMM1 LDS
// traffic and freeing the scheduler to run the W1 stream 2-3 ks deep.
// Waves 4-7 (G2): GEMM2 (Y += H*W2^T, c-strip 64), acc2 held over 16 chunks.
// One lgkm-only barrier per chunk; launch_bounds(512,4) caps VGPR at 128.
__global__ __launch_bounds__(512, 4) void ffn_kernel(
    const float* __restrict__ x, const float* __restrict__ b1,
    const float* __restrict__ b2, const unsigned short* __restrict__ W1b,
    const unsigned short* __restrict__ W2b, const int* __restrict__ cnt,
    const int* __restrict__ plist, const float2* __restrict__ wlist,
    const int* __restrict__ wl, float* __restrict__ out) {
  __shared__ unsigned short Xl[BM * NC];        // 32 KiB, swizzled, stride 512B
  __shared__ unsigned short Hl[2][BM * FFC];    // 2 x 16 KiB, swizzled, stride 256B

  int slot = blockIdx.x;
  if (slot >= wl[0]) return;
  int ent = wl[1 + slot];
  if (ent < 0) return;
  int pr = ent >> 12, pbase = ent & 4095;
  int e1 = pr >> 2, e2 = pr & 3;
  int n = cnt[pr];

  int tid = threadIdx.x, lane = tid & 63, wid = tid >> 6;
  int l15 = lane & 15;
  int kgrp = (lane >> 4) * 8;

  const int*    pl  = plist + pr * NPATCH + pbase;
  const float2* wlp = wlist + pr * NPATCH + pbase;

  float wvA[PPB], wvB[PPB];
#pragma unroll
  for (int q = 0; q < PPB; q++) {
    if (pbase + q < n) { float2 w = wlp[q]; wvA[q] = w.x; wvB[q] = w.y; }
    else { wvA[q] = 0.f; wvB[q] = 0.f; }
  }

  // ---- gather tokens -> bf16 LDS (all 8 waves) ----
  {
    int r  = tid >> 3;            // 0..63 token row
    int c0 = (tid & 7) * 32;      // 32 channels per thread
    int pid = (pbase + (r >> 4) < n) ? pl[r >> 4] : -1;
    int t = r & 15;
    if (pid >= 0) {
      int b = pid >> 10, pi = pid & 1023;
      int phi = pi >> 5, pwi = pi & 31;
      const float* src =
          x + (((size_t)(b * NH + phi * 4 + (t >> 2)) * NW) + pwi * 4 + (t & 3)) * NC + c0;
#pragma unroll
      for (int q = 0; q < 4; q++) {
        float4 v0 = *reinterpret_cast<const float4*>(src + q * 8);
        float4 v1 = *reinterpret_cast<const float4*>(src + q * 8 + 4);
        ushort8 h;
        h[0] = f2b(v0.x); h[1] = f2b(v0.y); h[2] = f2b(v0.z); h[3] = f2b(v0.w);
        h[4] = f2b(v1.x); h[5] = f2b(v1.y); h[6] = f2b(v1.z); h[7] = f2b(v1.w);
        int boff = (r * 512 + (c0 + q * 8) * 2) ^ ((r & 7) << 4);
        *reinterpret_cast<ushort8*>((char*)Xl + boff) = h;
      }
    } else {
      ushort8 h = (ushort8)0;
#pragma unroll
      for (int q = 0; q < 4; q++) {
        int boff = (r * 512 + (c0 + q * 8) * 2) ^ ((r & 7) << 4);
        *reinterpret_cast<ushort8*>((char*)Xl + boff) = h;
      }
    }
  }
  bar_lgkm();   // X visible to all waves

  if (wid < 4) {
    // ================= G1: producer =================
    int wf = wid;
    const unsigned short* W1A = W1b + (size_t)e1 * NFF * NC;
    const unsigned short* W1B = W1b + (size_t)e2 * NFF * NC;
    const float* b1A = b1 + e1 * NFF;
    const float* b1B = b1 + e2 * NFF;

    // preload X fragments for ks=0..3 (k = 0..127): 16 frags = 64 VGPR,
    // reused by every chunk -> ks 0-3 inner loop has no LDS reads.
    short8 bXr[4][4];   // [ks][nt]
#pragma unroll
    for (int ks = 0; ks < 4; ++ks) {
      int k = ks * 32 + kgrp;
#pragma unroll
      for (int nt = 0; nt < 4; nt++) {
        int row = nt * 16 + l15;
        int boff = (row * 512 + k * 2) ^ ((row & 7) << 4);
        bXr[ks][nt] = *reinterpret_cast<const short8*>((const char*)Xl + boff);
      }
    }

    f32x4 acc1[2][4];   // [ftl][nt]

#pragma unroll 1
    for (int j = 0; j < NCHUNK_TOT; ++j) {
      const unsigned short* W1e = (j < 8) ? W1A : W1B;
      const float* b1e = (j < 8) ? b1A : b1B;
      int fc = j & 7;
#pragma unroll
      for (int a = 0; a < 2; a++)
#pragma unroll
        for (int b = 0; b < 4; b++)
#pragma unroll
          for (int q = 0; q < 4; q++) acc1[a][b][q] = 0.f;

      // ---- ks 0-3: X from registers (no LDS) ----
#pragma unroll
      for (int ks = 0; ks < 4; ++ks) {
        int k = ks * 32 + kgrp;
        short8 aW[2];
#pragma unroll
        for (int ftl = 0; ftl < 2; ftl++) {
          int f = fc * FFC + wf * 32 + ftl * 16 + l15;
          aW[ftl] = *reinterpret_cast<const short8*>(W1e + (size_t)f * NC + k);
        }
        __builtin_amdgcn_s_setprio(1);
#pragma unroll
        for (int ftl = 0; ftl < 2; ftl++)
#pragma unroll
          for (int nt = 0; nt < 4; nt++)
            acc1[ftl][nt] = __builtin_amdgcn_mfma_f32_16x16x32_bf16(
                aW[ftl], bXr[ks][nt], acc1[ftl][nt], 0, 0, 0);
        __builtin_amdgcn_s_setprio(0);
      }
      // ---- ks 4-7: X from LDS ----
#pragma unroll
      for (int ks = 4; ks < 8; ++ks) {
        int k = ks * 32 + kgrp;
        short8 bX[4];
#pragma unroll
        for (int nt = 0; nt < 4; nt++) {
          int row = nt * 16 + l15;
          int boff = (row * 512 + k * 2) ^ ((row & 7) << 4);
          bX[nt] = *reinterpret_cast<const short8*>((const char*)Xl + boff);
        }
        short8 aW[2];
#pragma unroll
        for (int ftl = 0; ftl < 2; ftl++) {
          int f = fc * FFC + wf * 32 + ftl * 16 + l15;
          aW[ftl] = *reinterpret_cast<const short8*>(W1e + (size_t)f * NC + k);
        }
        __builtin_amdgcn_s_setprio(1);
#pragma unroll
        for (int ftl = 0; ftl < 2; ftl++)
#pragma unroll
          for (int nt = 0; nt < 4; nt++)
            acc1[ftl][nt] = __builtin_amdgcn_mfma_f32_16x16x32_bf16(
                aW[ftl], bX[nt], acc1[ftl][nt], 0, 0, 0);
        __builtin_amdgcn_s_setprio(0);
      }

      // bias + gelu + router-weight scale -> Hl (direct writes; dbuf makes
      // Hl[j&1] safe to overwrite after the previous barrier)
      unsigned short* Hb = &Hl[j & 1][0];
#pragma unroll
      for (int ftl = 0; ftl < 2; ftl++) {
        int f0 = wf * 32 + ftl * 16 + (lane >> 4) * 4;
        float4 bv = *reinterpret_cast<const float4*>(b1e + fc * FFC + f0);
#pragma unroll
        for (int nt = 0; nt < 4; nt++) {
          float w = (j < 8) ? wvA[nt] : wvB[nt];
          ushort4 hp;
          hp.x = f2b(gelu_f(acc1[ftl][nt][0] + bv.x) * w);
          hp.y = f2b(gelu_f(acc1[ftl][nt][1] + bv.y) * w);
          hp.z = f2b(gelu_f(acc1[ftl][nt][2] + bv.z) * w);
          hp.w = f2b(gelu_f(acc1[ftl][nt][3] + bv.w) * w);
          int token = nt * 16 + l15;
          int boff = (token * 256 + f0 * 2) ^ ((token & 7) << 4);
          *reinterpret_cast<ushort4*>((char*)Hb + boff) = hp;
        }
      }
      bar_lgkm();   // chunk j published; G2 done with Hl[j&1]'s previous tenant
    }
    // G1: 16 barriers
  } else {
    // ================= G2: consumer =================
    int wc = wid - 4;
    const unsigned short* W2A = W2b + (size_t)e1 * NC * NFF;
    const unsigned short* W2B = W2b + (size_t)e2 * NC * NFF;

    f32x4 acc2[4][4];   // [ct][rt]
#pragma unroll
    for (int a = 0; a < 4; a++)
#pragma unroll
      for (int b = 0; b < 4; b++)
#pragma unroll
        for (int q = 0; q < 4; q++) acc2[a][b][q] = 0.f;

    bar_lgkm();   // wait for chunk 0

#pragma unroll 1
    for (int j = 0; j < NCHUNK_TOT; ++j) {
      const unsigned short* W2e = (j < 8) ? W2A : W2B;
      int fcp = j & 7;
      const unsigned short* Hb = &Hl[j & 1][0];
#pragma unroll
      for (int ks = 0; ks < 4; ++ks) {        // K = FFC = 128
        int kf = ks * 32 + kgrp;
        short8 aH[4];
#pragma unroll
        for (int rt = 0; rt < 4; rt++) {
          int row = rt * 16 + l15;
          int boff = (row * 256 + kf * 2) ^ ((row & 7) << 4);
          aH[rt] = *reinterpret_cast<const short8*>((const char*)Hb + boff);
        }
        short8 bW[4];
#pragma unroll
        for (int ct = 0; ct < 4; ct++) {
          int c = wc * 64 + ct * 16 + l15;
          bW[ct] = *reinterpret_cast<const short8*>(
              W2e + (size_t)c * NFF + fcp * FFC + kf);
        }
        __builtin_amdgcn_s_setprio(1);
#pragma unroll
        for (int ct = 0; ct < 4; ct++)
#pragma unroll
          for (int rt = 0; rt < 4; rt++)
            acc2[ct][rt] = __builtin_amdgcn_mfma_f32_16x16x32_bf16(
                aH[rt], bW[ct], acc2[ct][rt], 0, 0, 0);
        __builtin_amdgcn_s_setprio(0);
      }
      if (j < NCHUNK_TOT - 1) bar_lgkm();   // total G2 barriers: 1 + 15 = 16
    }

    // ---- epilogue: out = acc2 + wA*b2[e1] + wB*b2[e2] ----
    float b2A4[4], b2B4[4];
#pragma unroll
    for (int ct = 0; ct < 4; ct++) {
      int c = wc * 64 + ct * 16 + l15;
      b2A4[ct] = b2[e1 * NC + c];
      b2B4[ct] = b2[e2 * NC + c];
    }
#pragma unroll
    for (int rt = 0; rt < 4; rt++) {
      if (pbase + rt >= n) continue;
      int pid = pl[rt];
      float wA = wvA[rt], wB = wvB[rt];
      int b = pid >> 10, pi = pid & 1023;
      int phi = pi >> 5, pwi = pi & 31;
#pragma unroll
      for (int i2 = 0; i2 < 4; i2++) {
        int t = (lane >> 4) * 4 + i2;   // token within patch
        float* dst =
            out + (((size_t)(b * NH + phi * 4 + (t >> 2)) * NW) + pwi * 4 + (t & 3)) * NC;
#pragma unroll
        for (int ct = 0; ct < 4; ct++) {
          int c = wc * 64 + ct * 16 + l15;
          dst[c] = acc2[ct][rt][i2] + wA * b2A4[ct] + wB * b2B4[ct];
        }
      }
    }
  }
}

extern "C" void kernel_launch(void* const* d_in, const int* in_sizes, int n_in,
                              void* d_out, int out_size, void* d_ws, size_t ws_size,
                              hipStream_t stream) {
  const float* x  = (const float*)d_in[0];
  const float* Wg = (const float*)d_in[1];
  const float* W1 = (const float*)d_in[2];
  const float* b1 = (const float*)d_in[3];
  const float* W2 = (const float*)d_in[4];
  const float* b2 = (const float*)d_in[5];
  float* out = (float*)d_out;

  char* ws = (char*)d_ws;
  unsigned short* W1b = (unsigned short*)ws;                                  // 2 MiB
  unsigned short* W2b = (unsigned short*)(ws + (size_t)2 * 1024 * 1024);      // 2 MiB
  int*    cnt   = (int*)(ws + (size_t)4 * 1024 * 1024);                       // 64 B
  int*    plist = (int*)(ws + (size_t)4 * 1024 * 1024 + 256);                 // 256 KiB
  float2* wlist = (float2*)(ws + (size_t)4 * 1024 * 1024 + 256 +
                            (size_t)NPAIR * NPATCH * sizeof(int));            // 512 KiB
  int*    wl    = (int*)(ws + (size_t)5 * 1024 * 1024);                       // ~33 KiB

  convert_kernel<<<dim3(4096), dim3(256), 0, stream>>>(W1, W2, W1b, W2b, cnt, NE * NFF * NC);
  router_kernel<<<dim3(NPATCH), dim3(256), 0, stream>>>(x, Wg, cnt, plist, wlist);
  worklist_kernel<<<dim3(1), dim3(64), 0, stream>>>(cnt, wl);

  // padded slots: 8 * max-class-tiles <= 8 * (1024 + 2) = 8208
  ffn_kernel<<<dim3(8208), dim3(512), 0, stream>>>(
      x, b1, b2, W1b, W2b, cnt, plist, wlist, wl, out);
}

// Round 11
// 616.969 us; speedup vs baseline: 1.0328x; 1.0328x over previous
//
#include <hip/hip_runtime.h>
#include <hip/hip_bf16.h>
#include <cstdint>

// Problem constants (fixed by the reference)
#define NB 4
#define NH 128
#define NW 128
#define NC 256
#define NFF 1024
#define NE 4
#define NPATCH 4096   // B * 32 * 32
#define NPAIR 16      // ordered expert pairs (i1*4+i2), 12 valid
#define PPB 4         // patches per ffn block
#define BM 64         // token rows per ffn block (PPB*16)
#define FFC 128       // FF chunk streamed through LDS
#define NCHUNK_TOT 16 // 2 experts x (NFF/FFC)
#define RING 3        // weight-ring depth (2-ahead prefetch)

typedef __attribute__((ext_vector_type(8))) short short8;
typedef __attribute__((ext_vector_type(8))) unsigned short ushort8;
typedef __attribute__((ext_vector_type(4))) float f32x4;

__device__ __forceinline__ unsigned short f2b(float f) {
  union { float f; uint32_t u; } v; v.f = f;
  uint32_t u = v.u + 0x7FFFu + ((v.u >> 16) & 1u);   // RNE
  return (unsigned short)(u >> 16);
}

// tanh-form GELU via sigmoid: x * sigmoid(1.5957691(x + 0.044715 x^3))
__device__ __forceinline__ float gelu_f(float v) {
  float u = v * v;
  float t = __builtin_fmaf(u, 0.044715f, 1.0f) * v;
  float e = __builtin_amdgcn_exp2f(t * -2.3022083f);   // exp(-1.59577*t)
  return v * __builtin_amdgcn_rcpf(1.0f + e);
}

// barrier that drains LDS ops only (no vmcnt drain -> DMA stays in flight)
__device__ __forceinline__ void bar_lgkm() {
  asm volatile("s_waitcnt lgkmcnt(0)" ::: "memory");
  __builtin_amdgcn_s_barrier();
}

// async global->LDS DMA, 16B per lane; LDS dest = wave-uniform base + lane*16
__device__ __forceinline__ void gload_lds16(const void* g, void* l) {
  __builtin_amdgcn_global_load_lds(
      (const __attribute__((address_space(1))) unsigned int*)g,
      (__attribute__((address_space(3))) unsigned int*)l, 16, 0, 0);
}

// ---------------- weight fp32 -> bf16 (+ cnt zeroing) ----------------
__global__ __launch_bounds__(256) void convert_kernel(
    const float* __restrict__ W1, const float* __restrict__ W2,
    unsigned short* __restrict__ W1b, unsigned short* __restrict__ W2b,
    int* __restrict__ cnt, int n) {
  int i = blockIdx.x * blockDim.x + threadIdx.x;
  if (i < NPAIR) cnt[i] = 0;
  if (i < n) {
    W1b[i] = f2b(W1[i]);
    W2b[i] = f2b(W2[i]);
  }
}

// ---------------- router: means -> logits -> softmax -> top2 -> pair bins ----------------
__global__ __launch_bounds__(256) void router_kernel(
    const float* __restrict__ x, const float* __restrict__ Wg,
    int* __restrict__ cnt, int* __restrict__ plist, float2* __restrict__ wlist) {
  int p = blockIdx.x;                 // 0..4095
  int b = p >> 10, pi = p & 1023;
  int phi = pi >> 5, pwi = pi & 31;
  int c = threadIdx.x;                // 0..255 = channel

  const float* base = x + (((size_t)(b * NH + phi * 4) * NW) + pwi * 4) * NC + c;
  float s = 0.f;
#pragma unroll
  for (int i = 0; i < 4; i++)
#pragma unroll
    for (int j = 0; j < 4; j++)
      s += base[(i * NW + j) * NC];
  float mean = s * (1.f / 16.f);

  __shared__ float m_lds[NC];
  __shared__ double logit_lds[NE];
  m_lds[c] = mean;
  __syncthreads();

  int wid = c >> 6, lane = c & 63;    // wave w computes logit for expert w
  {
    const float* wg = Wg + wid * NC;
    double acc = 0.0;
#pragma unroll
    for (int q = 0; q < 4; q++)
      acc += (double)m_lds[lane + q * 64] * (double)wg[lane + q * 64];
    for (int off = 32; off; off >>= 1) acc += __shfl_down(acc, off);
    if (lane == 0) logit_lds[wid] = acc;
  }
  __syncthreads();

  if (c == 0) {
    double l[NE], pp[NE];
    double mx = -1e300;
#pragma unroll
    for (int i = 0; i < NE; i++) { l[i] = logit_lds[i]; mx = fmax(mx, l[i]); }
    double sum = 0.0;
#pragma unroll
    for (int i = 0; i < NE; i++) { pp[i] = exp(l[i] - mx); sum += pp[i]; }
#pragma unroll
    for (int i = 0; i < NE; i++) pp[i] /= sum;
    // top-2, ties -> lower index (lax.top_k semantics)
    int i1 = 0; double p1 = pp[0];
    for (int i = 1; i < NE; i++) if (pp[i] > p1) { p1 = pp[i]; i1 = i; }
    int i2 = -1; double p2 = -1.0;
    for (int i = 0; i < NE; i++) {
      if (i == i1) continue;
      if (pp[i] > p2) { p2 = pp[i]; i2 = i; }
    }
    double den = p1 + p2 + 1e-9;
    float w1 = (float)(p1 / den), w2 = (float)(p2 / den);
    int pr = i1 * NE + i2;                         // ordered pair bin
    int pos = atomicAdd(&cnt[pr], 1);
    plist[pr * NPATCH + pos] = p;
    wlist[pr * NPATCH + pos] = make_float2(w1, w2);
  }
}

// ---------------- worklist: XCD-affine padded slots ----------------
__global__ __launch_bounds__(64) void worklist_kernel(
    const int* __restrict__ cnt, int* __restrict__ wl) {
  int lane = threadIdx.x;
  int cA[8], cB[8], mx = 0;
#pragma unroll
  for (int xc = 0; xc < 8; ++xc) {
    cA[xc] = (cnt[xc] + PPB - 1) / PPB;
    cB[xc] = (cnt[xc + 8] + PPB - 1) / PPB;
    int t = cA[xc] + cB[xc];
    mx = (t > mx) ? t : mx;
  }
  if (lane == 0) wl[0] = 8 * mx;
  int x = lane & 7, sub = lane >> 3;     // 8 writer lanes per class
  int nA = cA[x], tot = cA[x] + cB[x];
  for (int r = sub; r < mx; r += 8) {
    int ent = -1;
    if (r < nA) ent = (x << 12) | (r * PPB);
    else if (r < tot) ent = ((x + 8) << 12) | ((r - nA) * PPB);
    wl[1 + x + 8 * r] = ent;
  }
}

// ---------------- pair-FFN: role split + DMA weight rings (T3+T4) ----------------
// 512 thr / 8 waves, 144 KiB LDS -> 1 block/CU. G1 (waves 0-3): GEMM1 swapped
// (H^T = W1*X^T, f-strip 32) + bias(LDS) + GELU + router-scale -> dbuf Hl.
// G2 (waves 4-7): GEMM2 (Y += H*W2^T, c-strip 64), acc2 over 16 chunks.
// Weights arrive via per-wave PRIVATE LDS rings filled by global_load_lds:
// issue slice s+2 (CLAMPED to last slice -- NOT wrapped: seqlen % RING != 0,
// so a wrapped tail prefetch aliases the slot being read with DIFFERENT
// data; the R10 bug. Clamped re-issue rewrites identical bytes = benign),
// then s_waitcnt vmcnt(4/8) -> slice s resident. Lookahead depth 2
// (~2 ks-intervals) >= L2 latency, costs 0 VGPR. All non-DMA VMEM evicted
// from loops (bias in LDS; vmcnt(0) drain after gather) so the manual vmcnt
// immediates are exact. Barriers lgkm-only.
__global__ __launch_bounds__(512, 2) void ffn_kernel(
    const float* __restrict__ x, const float* __restrict__ b1,
    const float* __restrict__ b2, const unsigned short* __restrict__ W1b,
    const unsigned short* __restrict__ W2b, const int* __restrict__ cnt,
    const int* __restrict__ plist, const float2* __restrict__ wlist,
    const int* __restrict__ wl, float* __restrict__ out) {
  __shared__ unsigned short Xl[BM * NC];          // 32 KiB, swizzled, stride 512B
  __shared__ unsigned short Hl[2][BM * FFC];      // 32 KiB, swizzled, stride 256B
  __shared__ unsigned short W1r[4][RING][1024];   // 24 KiB: [kgrp4][f32] slices
  __shared__ unsigned short W2r[4][RING][2048];   // 48 KiB: [kgrp4][c64] slices
  __shared__ float b1lds[2 * NFF];                //  8 KiB

  int slotb = blockIdx.x;
  if (slotb >= wl[0]) return;
  int ent = wl[1 + slotb];
  if (ent < 0) return;
  int pr = ent >> 12, pbase = ent & 4095;
  int e1 = pr >> 2, e2 = pr & 3;
  int n = cnt[pr];

  int tid = threadIdx.x, lane = tid & 63, wid = tid >> 6;
  int l15 = lane & 15;
  int kgl = lane >> 4;                  // k-group of this lane

  const int*    pl  = plist + pr * NPATCH + pbase;
  const float2* wlp = wlist + pr * NPATCH + pbase;

  float wvA[PPB], wvB[PPB];
#pragma unroll
  for (int q = 0; q < PPB; q++) {
    if (pbase + q < n) { float2 w = wlp[q]; wvA[q] = w.x; wvB[q] = w.y; }
    else { wvA[q] = 0.f; wvB[q] = 0.f; }
  }

  // ---- stage b1 (both experts) into LDS (pre-drain VMEM) ----
  {
    int o = tid * 4;   // 512 threads x 4 floats = 2048
    const float* sp = (o < NFF) ? (b1 + e1 * NFF + o) : (b1 + e2 * NFF + (o - NFF));
    *reinterpret_cast<float4*>(&b1lds[o]) = *reinterpret_cast<const float4*>(sp);
  }

  // ---- gather tokens -> bf16 LDS (all 8 waves; pre-drain VMEM) ----
  {
    int r  = tid >> 3;            // 0..63 token row
    int c0 = (tid & 7) * 32;      // 32 channels per thread
    int pid = (pbase + (r >> 4) < n) ? pl[r >> 4] : -1;
    int t = r & 15;
    if (pid >= 0) {
      int b = pid >> 10, pi = pid & 1023;
      int phi = pi >> 5, pwi = pi & 31;
      const float* src =
          x + (((size_t)(b * NH + phi * 4 + (t >> 2)) * NW) + pwi * 4 + (t & 3)) * NC + c0;
#pragma unroll
      for (int q = 0; q < 4; q++) {
        float4 v0 = *reinterpret_cast<const float4*>(src + q * 8);
        float4 v1 = *reinterpret_cast<const float4*>(src + q * 8 + 4);
        ushort8 h;
        h[0] = f2b(v0.x); h[1] = f2b(v0.y); h[2] = f2b(v0.z); h[3] = f2b(v0.w);
        h[4] = f2b(v1.x); h[5] = f2b(v1.y); h[6] = f2b(v1.z); h[7] = f2b(v1.w);
        int boff = (r * 512 + (c0 + q * 8) * 2) ^ ((r & 7) << 4);
        *reinterpret_cast<ushort8*>((char*)Xl + boff) = h;
      }
    } else {
      ushort8 h = (ushort8)0;
#pragma unroll
      for (int q = 0; q < 4; q++) {
        int boff = (r * 512 + (c0 + q * 8) * 2) ^ ((r & 7) << 4);
        *reinterpret_cast<ushort8*>((char*)Xl + boff) = h;
      }
    }
  }

  // drain ALL prologue VMEM so manual vmcnt counts only the weight DMA
  asm volatile("s_waitcnt vmcnt(0)" ::: "memory");

  const unsigned short* W1A = W1b + (size_t)e1 * NFF * NC;
  const unsigned short* W1B = W1b + (size_t)e2 * NFF * NC;
  const unsigned short* W2A = W2b + (size_t)e1 * NC * NFF;
  const unsigned short* W2B = W2b + (size_t)e2 * NC * NFF;

  if (wid < 4) {
    // ================= G1: producer =================
    int wf = wid;

    // DMA one W1 slice [32 f][32 k] -> W1r[wf][s%3], layout [kgrp4][f32]x16B.
    // 2 instrs x 64 lanes x 16B. Tail CLAMPS to slice 127 (identical-byte
    // rewrite into its own slot; wrap would alias a live slot -- R10 bug).
    auto g1_issue = [&](int s) {
      s = (s > 127) ? 127 : s;
      int jj = s >> 3, kk = s & 7;
      const unsigned short* W1e = (jj < 8) ? W1A : W1B;
      int f0 = (jj & 7) * FFC + wf * 32;
      int k0 = kk * 32;
      int sl = s % 3;
#pragma unroll
      for (int q = 0; q < 2; q++) {
        const unsigned short* src =
            W1e + (size_t)(f0 + (lane & 31)) * NC + k0 + (q * 2 + (lane >> 5)) * 8;
        gload_lds16(src, (void*)&W1r[wf][sl][q * 512]);
      }
    };

    g1_issue(0);
    g1_issue(1);
    bar_lgkm();   // X + b1lds visible

    f32x4 acc1[2][4];
#pragma unroll 1
    for (int j = 0; j < NCHUNK_TOT; ++j) {
      int fc = j & 7;
#pragma unroll
      for (int a = 0; a < 2; a++)
#pragma unroll
        for (int b = 0; b < 4; b++)
#pragma unroll
          for (int q = 0; q < 4; q++) acc1[a][b][q] = 0.f;

#pragma unroll
      for (int ks = 0; ks < 8; ++ks) {
        int s = j * 8 + ks;
        g1_issue(s + 2);
        int sl = s % 3;
        asm volatile("s_waitcnt vmcnt(4)" ::: "memory");   // slice s resident
        short8 aW[2];
#pragma unroll
        for (int ftl = 0; ftl < 2; ftl++)
          aW[ftl] = *reinterpret_cast<const short8*>(
              &W1r[wf][sl][kgl * 256 + (ftl * 16 + l15) * 8]);
        int k = ks * 32 + kgl * 8;
        short8 bX[4];
#pragma unroll
        for (int nt = 0; nt < 4; nt++) {
          int row = nt * 16 + l15;
          int boff = (row * 512 + k * 2) ^ ((row & 7) << 4);
          bX[nt] = *reinterpret_cast<const short8*>((const char*)Xl + boff);
        }
        __builtin_amdgcn_s_setprio(1);
#pragma unroll
        for (int ftl = 0; ftl < 2; ftl++)
#pragma unroll
          for (int nt = 0; nt < 4; nt++)
            acc1[ftl][nt] = __builtin_amdgcn_mfma_f32_16x16x32_bf16(
                aW[ftl], bX[nt], acc1[ftl][nt], 0, 0, 0);
        __builtin_amdgcn_s_setprio(0);
      }

      // bias(LDS) + gelu + router-weight scale -> Hl[j&1]
      unsigned short* Hb = &Hl[j & 1][0];
      int sideOff = (j < 8) ? 0 : NFF;
#pragma unroll
      for (int ftl = 0; ftl < 2; ftl++) {
        int f0 = wf * 32 + ftl * 16 + (lane >> 4) * 4;
        float4 bv = *reinterpret_cast<const float4*>(&b1lds[sideOff + fc * FFC + f0]);
#pragma unroll
        for (int nt = 0; nt < 4; nt++) {
          float w = (j < 8) ? wvA[nt] : wvB[nt];
          ushort4 hp;
          hp.x = f2b(gelu_f(acc1[ftl][nt][0] + bv.x) * w);
          hp.y = f2b(gelu_f(acc1[ftl][nt][1] + bv.y) * w);
          hp.z = f2b(gelu_f(acc1[ftl][nt][2] + bv.z) * w);
          hp.w = f2b(gelu_f(acc1[ftl][nt][3] + bv.w) * w);
          int token = nt * 16 + l15;
          int boff = (token * 256 + f0 * 2) ^ ((token & 7) << 4);
          *reinterpret_cast<ushort4*>((char*)Hb + boff) = hp;
        }
      }
      bar_lgkm();   // chunk j published
    }
    // G1: 16 chunk barriers (+1 initial)
  } else {
    // ================= G2: consumer =================
    int wc = wid - 4;
    int c0g = wc * 64;

    // DMA one W2 slice [64 c][32 k] -> W2r[wc][s%3], layout [kgrp4][c64]x16B.
    // 4 instrs x 64 lanes x 16B; tail CLAMPS to slice 63 (see G1 note).
    auto g2_issue = [&](int s) {
      s = (s > 63) ? 63 : s;
      int jj = s >> 2, kk = s & 3;
      const unsigned short* W2e = (jj < 8) ? W2A : W2B;
      int k0 = (jj & 7) * FFC + kk * 32;
      int sl = s % 3;
      const unsigned short* srow = W2e + (size_t)(c0g + lane) * NFF + k0;
#pragma unroll
      for (int q = 0; q < 4; q++)
        gload_lds16(srow + q * 8, (void*)&W2r[wc][sl][q * 512]);
    };

    g2_issue(0);
    g2_issue(1);
    bar_lgkm();   // X + b1lds visible

    f32x4 acc2[4][4];   // [ct][rt]
#pragma unroll
    for (int a = 0; a < 4; a++)
#pragma unroll
      for (int b = 0; b < 4; b++)
#pragma unroll
        for (int q = 0; q < 4; q++) acc2[a][b][q] = 0.f;

    bar_lgkm();   // wait for chunk 0

#pragma unroll 1
    for (int j = 0; j < NCHUNK_TOT; ++j) {
      const unsigned short* Hb = &Hl[j & 1][0];
#pragma unroll
      for (int ks = 0; ks < 4; ++ks) {
        int s = j * 4 + ks;
        g2_issue(s + 2);
        int sl = s % 3;
        asm volatile("s_waitcnt vmcnt(8)" ::: "memory");   // slice s resident
        int kf = ks * 32 + kgl * 8;
        short8 aH[4];
#pragma unroll
        for (int rt = 0; rt < 4; rt++) {
          int row = rt * 16 + l15;
          int boff = (row * 256 + kf * 2) ^ ((row & 7) << 4);
          aH[rt] = *reinterpret_cast<const short8*>((const char*)Hb + boff);
        }
        short8 bW[4];
#pragma unroll
        for (int ct = 0; ct < 4; ct++)
          bW[ct] = *reinterpret_cast<const short8*>(
              &W2r[wc][sl][kgl * 512 + (ct * 16 + l15) * 8]);
        __builtin_amdgcn_s_setprio(1);
#pragma unroll
        for (int ct = 0; ct < 4; ct++)
#pragma unroll
          for (int rt = 0; rt < 4; rt++)
            acc2[ct][rt] = __builtin_amdgcn_mfma_f32_16x16x32_bf16(
                aH[rt], bW[ct], acc2[ct][rt], 0, 0, 0);
        __builtin_amdgcn_s_setprio(0);
      }
      if (j < NCHUNK_TOT - 1) bar_lgkm();
    }

    // ---- epilogue: out = acc2 + wA*b2[e1] + wB*b2[e2] ----
    float b2A4[4], b2B4[4];
#pragma unroll
    for (int ct = 0; ct < 4; ct++) {
      int c = wc * 64 + ct * 16 + l15;
      b2A4[ct] = b2[e1 * NC + c];
      b2B4[ct] = b2[e2 * NC + c];
    }
#pragma unroll
    for (int rt = 0; rt < 4; rt++) {
      if (pbase + rt >= n) continue;
      int pid = pl[rt];
      float wA = wvA[rt], wB = wvB[rt];
      int b = pid >> 10, pi = pid & 1023;
      int phi = pi >> 5, pwi = pi & 31;
#pragma unroll
      for (int i2 = 0; i2 < 4; i2++) {
        int t = (lane >> 4) * 4 + i2;   // token within patch
        float* dst =
            out + (((size_t)(b * NH + phi * 4 + (t >> 2)) * NW) + pwi * 4 + (t & 3)) * NC;
#pragma unroll
        for (int ct = 0; ct < 4; ct++) {
          int c = wc * 64 + ct * 16 + l15;
          dst[c] = acc2[ct][rt][i2] + wA * b2A4[ct] + wB * b2B4[ct];
        }
      }
    }
  }
}

extern "C" void kernel_launch(void* const* d_in, const int* in_sizes, int n_in,
                              void* d_out, int out_size, void* d_ws, size_t ws_size,
                              hipStream_t stream) {
  const float* x  = (const float*)d_in[0];
  const float* Wg = (const float*)d_in[1];
  const float* W1 = (const float*)d_in[2];
  const float* b1 = (const float*)d_in[3];
  const float* W2 = (const float*)d_in[4];
  const float* b2 = (const float*)d_in[5];
  float* out = (float*)d_out;

  char* ws = (char*)d_ws;
  unsigned short* W1b = (unsigned short*)ws;                                  // 2 MiB
  unsigned short* W2b = (unsigned short*)(ws + (size_t)2 * 1024 * 1024);      // 2 MiB
  int*    cnt   = (int*)(ws + (size_t)4 * 1024 * 1024);                       // 64 B
  int*    plist = (int*)(ws + (size_t)4 * 1024 * 1024 + 256);                 // 256 KiB
  float2* wlist = (float2*)(ws + (size_t)4 * 1024 * 1024 + 256 +
                            (size_t)NPAIR * NPATCH * sizeof(int));            // 512 KiB
  int*    wl    = (int*)(ws + (size_t)5 * 1024 * 1024);                       // ~33 KiB

  convert_kernel<<<dim3(4096), dim3(256), 0, stream>>>(W1, W2, W1b, W2b, cnt, NE * NFF * NC);
  router_kernel<<<dim3(NPATCH), dim3(256), 0, stream>>>(x, Wg, cnt, plist, wlist);
  worklist_kernel<<<dim3(1), dim3(64), 0, stream>>>(cnt, wl);

  // padded slots: 8 * max-class-tiles <= 8 * (1024 + 2) = 8208
  ffn_kernel<<<dim3(8208), dim3(512), 0, stream>>>(
      x, b1, b2, W1b, W2b, cnt, plist, wlist, wl, out);
}

// Round 13
// 490.119 us; speedup vs baseline: 1.3001x; 1.2588x over previous
//
#include <hip/hip_runtime.h>
#include <hip/hip_bf16.h>
#include <cstdint>

// Problem constants (fixed by the reference)
#define NB 4
#define NH 128
#define NW 128
#define NC 256
#define NFF 1024
#define NE 4
#define NPATCH 4096   // B * 32 * 32
#define NPAIR 16      // ordered expert pairs (i1*4+i2), 12 valid
#define PPB 6         // patches per ffn block
#define BM 96         // token rows per ffn block (PPB*16)
#define FFC 128       // FF chunk
#define NCHUNK_TOT 16 // 2 experts x (NFF/FFC)

typedef __attribute__((ext_vector_type(8))) short short8;
typedef __attribute__((ext_vector_type(8))) unsigned short ushort8;
typedef __attribute__((ext_vector_type(16))) float f32x16;

__device__ __forceinline__ unsigned short f2b(float f) {
  union { float f; uint32_t u; } v; v.f = f;
  uint32_t u = v.u + 0x7FFFu + ((v.u >> 16) & 1u);   // RNE
  return (unsigned short)(u >> 16);
}

__device__ __forceinline__ float gelu_f(float v) {
  float u = v * v;
  float t = __builtin_fmaf(u, 0.044715f, 1.0f) * v;
  float e = __builtin_amdgcn_exp2f(t * -2.3022083f);
  return v * __builtin_amdgcn_rcpf(1.0f + e);
}

// barrier that drains LDS ops only (vm DMA stays in flight)
__device__ __forceinline__ void bar_lgkm() {
  asm volatile("s_waitcnt lgkmcnt(0)" ::: "memory");
  __builtin_amdgcn_s_barrier();
}

__device__ __forceinline__ void gload_lds16(const void* g, void* l) {
  __builtin_amdgcn_global_load_lds(
      (const __attribute__((address_space(1))) unsigned int*)g,
      (__attribute__((address_space(3))) unsigned int*)l, 16, 0, 0);
}

// ---------------- weight fp32 -> bf16 (+ cnt zeroing) ----------------
__global__ __launch_bounds__(256) void convert_kernel(
    const float* __restrict__ W1, const float* __restrict__ W2,
    unsigned short* __restrict__ W1b, unsigned short* __restrict__ W2b,
    int* __restrict__ cnt, int n) {
  int i = blockIdx.x * blockDim.x + threadIdx.x;
  if (i < NPAIR) cnt[i] = 0;
  if (i < n) {
    W1b[i] = f2b(W1[i]);
    W2b[i] = f2b(W2[i]);
  }
}

// ---------------- router ----------------
__global__ __launch_bounds__(256) void router_kernel(
    const float* __restrict__ x, const float* __restrict__ Wg,
    int* __restrict__ cnt, int* __restrict__ plist, float2* __restrict__ wlist) {
  int p = blockIdx.x;
  int b = p >> 10, pi = p & 1023;
  int phi = pi >> 5, pwi = pi & 31;
  int c = threadIdx.x;

  const float* base = x + (((size_t)(b * NH + phi * 4) * NW) + pwi * 4) * NC + c;
  float s = 0.f;
#pragma unroll
  for (int i = 0; i < 4; i++)
#pragma unroll
    for (int j = 0; j < 4; j++)
      s += base[(i * NW + j) * NC];
  float mean = s * (1.f / 16.f);

  __shared__ float m_lds[NC];
  __shared__ double logit_lds[NE];
  m_lds[c] = mean;
  __syncthreads();

  int wid = c >> 6, lane = c & 63;
  {
    const float* wg = Wg + wid * NC;
    double acc = 0.0;
#pragma unroll
    for (int q = 0; q < 4; q++)
      acc += (double)m_lds[lane + q * 64] * (double)wg[lane + q * 64];
    for (int off = 32; off; off >>= 1) acc += __shfl_down(acc, off);
    if (lane == 0) logit_lds[wid] = acc;
  }
  __syncthreads();

  if (c == 0) {
    double l[NE], pp[NE];
    double mx = -1e300;
#pragma unroll
    for (int i = 0; i < NE; i++) { l[i] = logit_lds[i]; mx = fmax(mx, l[i]); }
    double sum = 0.0;
#pragma unroll
    for (int i = 0; i < NE; i++) { pp[i] = exp(l[i] - mx); sum += pp[i]; }
#pragma unroll
    for (int i = 0; i < NE; i++) pp[i] /= sum;
    int i1 = 0; double p1 = pp[0];
    for (int i = 1; i < NE; i++) if (pp[i] > p1) { p1 = pp[i]; i1 = i; }
    int i2 = -1; double p2 = -1.0;
    for (int i = 0; i < NE; i++) {
      if (i == i1) continue;
      if (pp[i] > p2) { p2 = pp[i]; i2 = i; }
    }
    double den = p1 + p2 + 1e-9;
    float w1 = (float)(p1 / den), w2 = (float)(p2 / den);
    int pr = i1 * NE + i2;
    int pos = atomicAdd(&cnt[pr], 1);
    plist[pr * NPATCH + pos] = p;
    wlist[pr * NPATCH + pos] = make_float2(w1, w2);
  }
}

// ---------------- worklist: XCD-affine padded slots ----------------
__global__ __launch_bounds__(64) void worklist_kernel(
    const int* __restrict__ cnt, int* __restrict__ wl) {
  int lane = threadIdx.x;
  int cA[8], cB[8], mx = 0;
#pragma unroll
  for (int xc = 0; xc < 8; ++xc) {
    cA[xc] = (cnt[xc] + PPB - 1) / PPB;
    cB[xc] = (cnt[xc + 8] + PPB - 1) / PPB;
    int t = cA[xc] + cB[xc];
    mx = (t > mx) ? t : mx;
  }
  if (lane == 0) wl[0] = 8 * mx;
  int x = lane & 7, sub = lane >> 3;
  int nA = cA[x], tot = cA[x] + cB[x];
  for (int r = sub; r < mx; r += 8) {
    int ent = -1;
    if (r < nA) ent = (x << 12) | (r * PPB);
    else if (r < tot) ent = ((x + 8) << 12) | ((r - nA) * PPB);
    wl[1 + x + 8 * r] = ent;
  }
}

// ---------------- pair-FFN: 32x32x16 MFMA, fragment-order LDS, DMA dbuf ----------------
// Identical to R12 except the G1 router-weight fix: GEMM1's D[f][t] has
// token = lane&31 (C/D col=lane), so the per-patch weight is selected by
// (l31>>4), NOT by the f-quad index q (R12 bug). Selection done with
// compile-time array indices + v_cndmask (runtime index would spill, rule #20).
__global__ __launch_bounds__(512, 2) void ffn_kernel(
    const float* __restrict__ x, const float* __restrict__ b1,
    const float* __restrict__ b2, const unsigned short* __restrict__ W1b,
    const unsigned short* __restrict__ W2b, const int* __restrict__ cnt,
    const int* __restrict__ plist, const float2* __restrict__ wlist,
    const int* __restrict__ wl, float* __restrict__ out) {
  __shared__ unsigned short Xf[3 * 16 * 512];   // 48 KiB: [tt][kk] frag pages
  __shared__ unsigned short Hf[3 * 8 * 512];    // 24 KiB: [tt][kkf] frag pages
  __shared__ unsigned short W1r[4][2][4 * 512]; // 32 KiB: per-G1-wave dbuf
  __shared__ unsigned short W2r[4][2][4 * 512]; // 32 KiB: per-G2-wave dbuf
  __shared__ float b1l[2 * NFF];                //  8 KiB

  int slotb = blockIdx.x;
  if (slotb >= wl[0]) return;
  int ent = wl[1 + slotb];
  if (ent < 0) return;
  int pr = ent >> 12, pbase = ent & 4095;
  int e1 = pr >> 2, e2 = pr & 3;
  int n = cnt[pr];

  int tid = threadIdx.x, lane = tid & 63, wid = tid >> 6;
  int l31 = lane & 31, lh = lane >> 5;   // 32x32 frag: row/col = l31, k-half = lh

  const int*    pl  = plist + pr * NPATCH + pbase;
  const float2* wlp = wlist + pr * NPATCH + pbase;

  float wvA[PPB], wvB[PPB];
#pragma unroll
  for (int q = 0; q < PPB; q++) {
    if (pbase + q < n) { float2 w = wlp[q]; wvA[q] = w.x; wvB[q] = w.y; }
    else { wvA[q] = 0.f; wvB[q] = 0.f; }
  }

  // ---- prologue staging: threads 0-383 gather X into fragment pages;
  //      threads 384-511 stage b1 (both experts) into LDS ----
  if (tid < 384) {
    int r  = tid >> 2;            // 0..95 token row
    int c0 = (tid & 3) * 64;      // 64 channels
    int pid = (pbase + (r >> 4) < n) ? pl[r >> 4] : -1;
    int t = r & 15;
    int tt = r >> 5, t32 = r & 31;
    if (pid >= 0) {
      int b = pid >> 10, pi = pid & 1023;
      int phi = pi >> 5, pwi = pi & 31;
      const float* src =
          x + (((size_t)(b * NH + phi * 4 + (t >> 2)) * NW) + pwi * 4 + (t & 3)) * NC + c0;
#pragma unroll
      for (int kb = 0; kb < 8; kb++) {
        float4 v0 = *reinterpret_cast<const float4*>(src + kb * 8);
        float4 v1 = *reinterpret_cast<const float4*>(src + kb * 8 + 4);
        ushort8 h;
        h[0] = f2b(v0.x); h[1] = f2b(v0.y); h[2] = f2b(v0.z); h[3] = f2b(v0.w);
        h[4] = f2b(v1.x); h[5] = f2b(v1.y); h[6] = f2b(v1.z); h[7] = f2b(v1.w);
        int k = c0 + kb * 8;
        int uidx = (tt * 16 + (k >> 4)) * 512 + (((k >> 3) & 1) * 32 + t32) * 8;
        *reinterpret_cast<ushort8*>(&Xf[uidx]) = h;
      }
    } else {
      ushort8 h = (ushort8)0;
#pragma unroll
      for (int kb = 0; kb < 8; kb++) {
        int k = c0 + kb * 8;
        int uidx = (tt * 16 + (k >> 4)) * 512 + (((k >> 3) & 1) * 32 + t32) * 8;
        *reinterpret_cast<ushort8*>(&Xf[uidx]) = h;
      }
    }
  } else {
    int o = (tid - 384) * 16;
#pragma unroll
    for (int q = 0; q < 4; q++) {
      int idx = o + q * 4;
      const float* sp = (idx < NFF) ? (b1 + e1 * NFF + idx) : (b1 + e2 * NFF + (idx - NFF));
      *reinterpret_cast<float4*>(&b1l[idx]) = *reinterpret_cast<const float4*>(sp);
    }
  }

  // drain ALL prologue VMEM so vmcnt counts only weight DMA
  asm volatile("s_waitcnt vmcnt(0)" ::: "memory");

  const unsigned short* W1A = W1b + (size_t)e1 * NFF * NC;
  const unsigned short* W1B = W1b + (size_t)e2 * NFF * NC;
  const unsigned short* W2A = W2b + (size_t)e1 * NC * NFF;
  const unsigned short* W2B = W2b + (size_t)e2 * NC * NFF;

  if (wid < 4) {
    // ================= G1: producer =================
    int wf = wid;
    // issue W1 K-step slice g (g = j*4+s, 0..63): 4 frag pages, 4KB
    auto g1_issue = [&](int g) {
      g = (g > 63) ? 63 : g;
      int jj = g >> 2, st = g & 3;
      const unsigned short* W1e = (jj < 8) ? W1A : W1B;
      int fg = (jj & 7) * FFC + wf * 32 + l31;
      int slot = g & 1;
#pragma unroll
      for (int q = 0; q < 4; q++) {
        const unsigned short* src = W1e + (size_t)fg * NC + st * 64 + q * 16 + lh * 8;
        gload_lds16(src, (void*)&W1r[wf][slot][q * 512]);
      }
    };

    g1_issue(0);
    bar_lgkm();   // Xf + b1l visible

    f32x16 acc0, acc1v, acc2v;
    ushort4 hreg[12];

#pragma unroll 1
    for (int j = 0; j < NCHUNK_TOT; ++j) {
      int fc = j & 7;
      int sideOff = (j < 8) ? 0 : NFF;
      acc0 = (f32x16)0.f; acc1v = (f32x16)0.f; acc2v = (f32x16)0.f;

#pragma unroll
      for (int s = 0; s < 4; ++s) {     // K-steps of 64 (K = 256)
        g1_issue(j * 4 + s + 1);
        asm volatile("s_waitcnt vmcnt(4)" ::: "memory");  // slice s resident
        int slot = s & 1;
#pragma unroll
        for (int kq = 0; kq < 4; ++kq) {
          int kk = s * 4 + kq;
          short8 aW = *reinterpret_cast<const short8*>(&W1r[wf][slot][kq * 512 + lane * 8]);
          short8 bX0 = *reinterpret_cast<const short8*>(&Xf[(0 * 16 + kk) * 512 + lane * 8]);
          short8 bX1 = *reinterpret_cast<const short8*>(&Xf[(1 * 16 + kk) * 512 + lane * 8]);
          short8 bX2 = *reinterpret_cast<const short8*>(&Xf[(2 * 16 + kk) * 512 + lane * 8]);
          acc0  = __builtin_amdgcn_mfma_f32_32x32x16_bf16(aW, bX0, acc0, 0, 0, 0);
          acc1v = __builtin_amdgcn_mfma_f32_32x32x16_bf16(aW, bX1, acc1v, 0, 0, 0);
          acc2v = __builtin_amdgcn_mfma_f32_32x32x16_bf16(aW, bX2, acc2v, 0, 0, 0);
        }
      }

      // GELU + router-scale -> hreg. D[f][t]: t = l31 (col=lane), so the
      // patch weight is chosen by l31>>4 (FIX: R12 used the f-quad q here).
#pragma unroll
      for (int tt = 0; tt < 3; ++tt) {
        const f32x16& A = (tt == 0) ? acc0 : (tt == 1) ? acc1v : acc2v;
        float wlo = (j < 8) ? wvA[tt * 2]     : wvB[tt * 2];
        float whi = (j < 8) ? wvA[tt * 2 + 1] : wvB[tt * 2 + 1];
        float w = (l31 >= 16) ? whi : wlo;
#pragma unroll
        for (int q = 0; q < 4; ++q) {
          int qs = q * 8 + lh * 4;                  // f-local base of this reg-quad
          float4 bv = *reinterpret_cast<const float4*>(&b1l[sideOff + fc * FFC + wf * 32 + qs]);
          ushort4 hp;
          hp.x = f2b(gelu_f(A[q * 4 + 0] + bv.x) * w);
          hp.y = f2b(gelu_f(A[q * 4 + 1] + bv.y) * w);
          hp.z = f2b(gelu_f(A[q * 4 + 2] + bv.z) * w);
          hp.w = f2b(gelu_f(A[q * 4 + 3] + bv.w) * w);
          hreg[tt * 4 + q] = hp;
        }
      }
      bar_lgkm();   // BAR1: G2 done reading Hf (chunk j-1)
#pragma unroll
      for (int tt = 0; tt < 3; ++tt) {
#pragma unroll
        for (int q = 0; q < 4; ++q) {
          int qs = q * 8 + lh * 4;
          int page = tt * 8 + wf * 2 + (qs >> 4);
          int uidx = page * 512 + (((qs >> 3) & 1) * 32 + l31) * 8 + (qs & 4);
          *reinterpret_cast<ushort4*>(&Hf[uidx]) = hreg[tt * 4 + q];
        }
      }
      bar_lgkm();   // BAR2: Hf(j) published
    }
    // G1 exits (barriers: 1 + 32)
  } else {
    // ================= G2: consumer =================
    int wc = wid - 4;
    // issue W2 K-step slice g (g = jc*4+s, 0..63): 4 pages (2 ctile x 2 kk)
    auto g2_issue = [&](int g) {
      g = (g > 63) ? 63 : g;
      int jj = g >> 2, st = g & 3;
      const unsigned short* W2e = (jj < 8) ? W2A : W2B;
      int fcn = jj & 7;
      int slot = g & 1;
#pragma unroll
      for (int q = 0; q < 4; q++) {
        int ct = q >> 1, kkis = q & 1;
        const unsigned short* src = W2e +
            (size_t)(wc * 64 + ct * 32 + l31) * NFF +
            fcn * FFC + st * 32 + kkis * 16 + lh * 8;
        gload_lds16(src, (void*)&W2r[wc][slot][q * 512]);
      }
    };

    g2_issue(0);
    bar_lgkm();   // Xf + b1l visible (barrier #0)

    f32x16 y00 = (f32x16)0.f, y01 = (f32x16)0.f, y02 = (f32x16)0.f;
    f32x16 y10 = (f32x16)0.f, y11 = (f32x16)0.f, y12 = (f32x16)0.f;

    // consume chunk jc from Hf (4 K-steps of 32f)
    auto consume = [&](int jc) {
#pragma unroll
      for (int s = 0; s < 4; ++s) {
        g2_issue(jc * 4 + s + 1);
        asm volatile("s_waitcnt vmcnt(4)" ::: "memory");
        int slot = s & 1;
#pragma unroll
        for (int kkis = 0; kkis < 2; ++kkis) {
          int kkf = s * 2 + kkis;
          short8 aH0 = *reinterpret_cast<const short8*>(&Hf[(0 * 8 + kkf) * 512 + lane * 8]);
          short8 aH1 = *reinterpret_cast<const short8*>(&Hf[(1 * 8 + kkf) * 512 + lane * 8]);
          short8 aH2 = *reinterpret_cast<const short8*>(&Hf[(2 * 8 + kkf) * 512 + lane * 8]);
          short8 bW0 = *reinterpret_cast<const short8*>(&W2r[wc][slot][(0 * 2 + kkis) * 512 + lane * 8]);
          short8 bW1 = *reinterpret_cast<const short8*>(&W2r[wc][slot][(1 * 2 + kkis) * 512 + lane * 8]);
          y00 = __builtin_amdgcn_mfma_f32_32x32x16_bf16(aH0, bW0, y00, 0, 0, 0);
          y01 = __builtin_amdgcn_mfma_f32_32x32x16_bf16(aH1, bW0, y01, 0, 0, 0);
          y02 = __builtin_amdgcn_mfma_f32_32x32x16_bf16(aH2, bW0, y02, 0, 0, 0);
          y10 = __builtin_amdgcn_mfma_f32_32x32x16_bf16(aH0, bW1, y10, 0, 0, 0);
          y11 = __builtin_amdgcn_mfma_f32_32x32x16_bf16(aH1, bW1, y11, 0, 0, 0);
          y12 = __builtin_amdgcn_mfma_f32_32x32x16_bf16(aH2, bW1, y12, 0, 0, 0);
        }
      }
    };

#pragma unroll 1
    for (int j = 0; j < NCHUNK_TOT; ++j) {
      if (j > 0) consume(j - 1);
      bar_lgkm();   // BAR1
      bar_lgkm();   // BAR2
    }
    consume(NCHUNK_TOT - 1);   // drain (no barriers; G1 has exited)

    // ---- epilogue: out[t][c] = Y + wA*b2A + wB*b2B ----
#pragma unroll
    for (int ct = 0; ct < 2; ++ct) {
      int cc = wc * 64 + ct * 32 + l31;
      float bA = b2[e1 * NC + cc];
      float bB = b2[e2 * NC + cc];
#pragma unroll
      for (int tt = 0; tt < 3; ++tt) {
        const f32x16& Y = (ct == 0) ? ((tt == 0) ? y00 : (tt == 1) ? y01 : y02)
                                    : ((tt == 0) ? y10 : (tt == 1) ? y11 : y12);
#pragma unroll
        for (int q = 0; q < 4; ++q) {
          int pslot = tt * 2 + (q >> 1);
          if (pbase + pslot >= n) continue;
          int pid = pl[pslot];
          float wA = wvA[pslot], wB = wvB[pslot];
          int b = pid >> 10, pi = pid & 1023;
          int phi = pi >> 5, pwi = pi & 31;
          float bias = wA * bA + wB * bB;
#pragma unroll
          for (int i = 0; i < 4; ++i) {
            int tok = 8 * (q & 1) + 4 * lh + i;
            float* dst =
                out + (((size_t)(b * NH + phi * 4 + (tok >> 2)) * NW) + pwi * 4 + (tok & 3)) * NC;
            dst[cc] = Y[q * 4 + i] + bias;
          }
        }
      }
    }
  }
}

extern "C" void kernel_launch(void* const* d_in, const int* in_sizes, int n_in,
                              void* d_out, int out_size, void* d_ws, size_t ws_size,
                              hipStream_t stream) {
  const float* x  = (const float*)d_in[0];
  const float* Wg = (const float*)d_in[1];
  const float* W1 = (const float*)d_in[2];
  const float* b1 = (const float*)d_in[3];
  const float* W2 = (const float*)d_in[4];
  const float* b2 = (const float*)d_in[5];
  float* out = (float*)d_out;

  char* ws = (char*)d_ws;
  unsigned short* W1b = (unsigned short*)ws;                                  // 2 MiB
  unsigned short* W2b = (unsigned short*)(ws + (size_t)2 * 1024 * 1024);      // 2 MiB
  int*    cnt   = (int*)(ws + (size_t)4 * 1024 * 1024);                       // 64 B
  int*    plist = (int*)(ws + (size_t)4 * 1024 * 1024 + 256);                 // 256 KiB
  float2* wlist = (float2*)(ws + (size_t)4 * 1024 * 1024 + 256 +
                            (size_t)NPAIR * NPATCH * sizeof(int));            // 512 KiB
  int*    wl    = (int*)(ws + (size_t)5 * 1024 * 1024);                       // ~44 KiB

  convert_kernel<<<dim3(4096), dim3(256), 0, stream>>>(W1, W2, W1b, W2b, cnt, NE * NFF * NC);
  router_kernel<<<dim3(NPATCH), dim3(256), 0, stream>>>(x, Wg, cnt, plist, wlist);
  worklist_kernel<<<dim3(1), dim3(64), 0, stream>>>(cnt, wl);

  // padded slots: 8 * max-class-tiles <= 8 * (ceil(4096/6)+1) = 5472
  ffn_kernel<<<dim3(5472), dim3(512), 0, stream>>>(
      x, b1, b2, W1b, W2b, cnt, plist, wlist, wl, out);
}